// Round 13
// baseline (208.015 us; speedup 1.0000x reference)
//
#include <hip/hip_runtime.h>
#include <cstdint>
#include <cstddef>

// ---------------------------------------------------------------------------
// KANAdaptiveFusion: fused = [bases(x) | silu(x)] @ W'^T ; LayerNorm over OUT.
// Round 13: faithful m201-style 8-phase port. 512 thr, 8 waves 2m x 4n,
// wave tile 64x128 (acc 4x8 = 128 VGPR, 2 waves/SIMD). Per BK=64 chunk:
// 4 phases over (ks, n-half), each {ds_read <=8 || stage -> barrier ->
// lgkmcnt(0)+sched_barrier -> setprio(1) 16 MFMA setprio(0) -> barrier}.
// All B(t+1) gloads + x(t+2) issued in P0 (3 phases of cover -> end-of-chunk
// vmcnt(0) is free). A dbuf 32 KB + B dbuf 128 KB = 160 KB. Chunk-XOR
// swizzle, pre-swizzled W', diet basis, split-K=2 (grid 128x2).
// ---------------------------------------------------------------------------

#define BATCH    16384
#define OUT_DIM  512
#define KTOT     9216
#define BM       128
#define BK       64
#define NCHUNK        144
#define SPLINE_CHUNKS 128

typedef __attribute__((ext_vector_type(8))) short  short8;
typedef __attribute__((ext_vector_type(4))) float  f32x4;

static __device__ __forceinline__ unsigned short f2bf(float f) {
    unsigned int u = __float_as_uint(f);
    unsigned int r = u + 0x7fffu + ((u >> 16) & 1u);
    return (unsigned short)(r >> 16);
}

// ---------------------------------------------------------------------------
// prep: W' bf16 (OUT_DIM x KTOT row-major) PRE-SWIZZLED: within each 64-elem
// K-block, 8-element chunk cl stored at chunk cl ^ (o&7).  (proven)
// ---------------------------------------------------------------------------
__global__ void prep_w_kernel(const float* __restrict__ bw,
                              const float* __restrict__ sw,
                              const float* __restrict__ sc,
                              unsigned short* __restrict__ Wp) {
    int t = blockIdx.x * 256 + threadIdx.x;      // < 512 * 1152
    int o = t / 1152;
    int g = t - o * 1152;
    int sz = o & 7;
    unsigned short o8[8];
    size_t dst;
    if (g < 1024) {                 // spline region: i = g, coefs 0..7
        float s = sc[(size_t)o * 1024 + g];
        const float* w = sw + ((size_t)o * 1024 + g) * 8;
        #pragma unroll
        for (int k = 0; k < 8; ++k) o8[k] = f2bf(w[k] * s);
        dst = (size_t)o * KTOT + (size_t)(g >> 3) * 64 + (size_t)(((g & 7) ^ sz)) * 8;
    } else {                        // base region
        int gi = g - 1024;          // 0..127
        const float* w = bw + (size_t)o * 1024 + gi * 8;
        #pragma unroll
        for (int k = 0; k < 8; ++k) o8[k] = f2bf(w[k]);
        dst = (size_t)o * KTOT + (size_t)8192 + (size_t)(gi >> 3) * 64 + (size_t)(((gi & 7) ^ sz)) * 8;
    }
    *reinterpret_cast<short8*>(Wp + dst) = *reinterpret_cast<const short8*>(o8);
}

// ---------------------------------------------------------------------------
// basis8: cubic B-spline bases packed as 4 u32 (8 bf16). Diet version (R9).
// ---------------------------------------------------------------------------
static __device__ __forceinline__ void basis8(float x, unsigned* out) {
    float tpos = (x + 2.2f) * 2.5f;          // knots -2.2 + 0.4*t
    float fj   = floorf(tpos);
    int   j    = (int)fj;
    float u  = tpos - fj;
    float v  = 1.f - u;
    float u2 = u * u;
    float u3 = u2 * u;
    const float c6 = 1.f / 6.f;
    float n0 = v * v * v * c6;
    float n3 = u3 * c6;
    float n1 = __builtin_fmaf(0.5f, u3, __builtin_fmaf(-1.f, u2, 4.f * c6));
    float n2 = 1.f - n0 - n1 - n3;
    unsigned p0, p1;
    asm("v_cvt_pk_bf16_f32 %0, %1, %2" : "=v"(p0) : "v"(n0), "v"(n1));
    asm("v_cvt_pk_bf16_f32 %0, %1, %2" : "=v"(p1) : "v"(n2), "v"(n3));
    int sh = (j << 4) - 48;                  // bf16-slot shift *16
    int c  = sh & 16;
    int w  = (sh - c) >> 5;                  // signed word shift
    unsigned long long P = ((unsigned long long)p1 << 32) | p0;
    unsigned long long T = P << c;
    unsigned t0 = (unsigned)T;
    unsigned t1 = (unsigned)(T >> 32);
    unsigned t2 = c ? (p1 >> 16) : 0u;
    #pragma unroll
    for (int i = 0; i < 4; ++i) {
        unsigned r = 0u;
        r = (w == i    ) ? t0 : r;
        r = (w == i - 1) ? t1 : r;
        r = (w == i - 2) ? t2 : r;
        out[i] = r;
    }
}

#define PHASE_PRE()  do { __builtin_amdgcn_s_barrier(); \
    asm volatile("s_waitcnt lgkmcnt(0)" ::: "memory"); \
    __builtin_amdgcn_sched_barrier(0); } while (0)
#define PHASE_POST() do { __builtin_amdgcn_sched_barrier(0); \
    __builtin_amdgcn_s_barrier(); } while (0)

// ---------------------------------------------------------------------------
// GEMM: 128x512 tile, BK=64, 512 threads (8 waves 2m x 4n; 64x128/wave).
// ---------------------------------------------------------------------------
template<bool SPLIT>
__launch_bounds__(512, 2)
__global__ void kan_gemm_kernel(const float* __restrict__ rgb,
                                const float* __restrict__ tac,
                                const unsigned short* __restrict__ Wp,
                                float* __restrict__ dest_base) {
    __shared__ unsigned short At[2][BM][BK];        //  32 KB, chunk-swizzled
    __shared__ unsigned short Bt[2][OUT_DIM][BK];   // 128 KB, chunk-swizzled

    const int tid  = threadIdx.x;
    const int lane = tid & 63;
    const int wid  = tid >> 6;
    const int b0   = blockIdx.x * BM;
    const int wr   = wid & 1;                       // 2 m-waves (64 rows)
    const int wc   = wid >> 1;                      // 4 n-waves (128 cols)
    const int ksp  = SPLIT ? (int)blockIdx.y : 0;
    const int kc0  = SPLIT ? (ksp ? 72 : 0)             : 0;
    const int kcS  = SPLIT ? (ksp ? SPLINE_CHUNKS : 72) : SPLINE_CHUNKS;
    const int kc1  = SPLIT ? (ksp ? NCHUNK : 72)        : NCHUNK;
    float* dest = dest_base + (size_t)ksp * BATCH * OUT_DIM;

    f32x4 acc[4][8];                                // 128 VGPR
    #pragma unroll
    for (int m = 0; m < 4; ++m)
        #pragma unroll
        for (int n = 0; n < 8; ++n)
            acc[m][n] = (f32x4){0.f, 0.f, 0.f, 0.f};

    auto readA = [&](short8* Af, int ab, int ks) {  // 4 x ds_read_b128
        int cb = ks * 4 + (lane >> 4);
        #pragma unroll
        for (int m = 0; m < 4; ++m) {
            int row = wr * 64 + m * 16 + (lane & 15);
            Af[m] = *reinterpret_cast<const short8*>(&At[ab][row][(cb ^ (row & 7)) * 8]);
        }
    };
    auto readB = [&](short8* Bf, int bb, int ks, int nh) {  // 4 x ds_read_b128
        int cb = ks * 4 + (lane >> 4);
        #pragma unroll
        for (int n = 0; n < 4; ++n) {
            int row = wc * 128 + (nh + n) * 16 + (lane & 15);
            Bf[n] = *reinterpret_cast<const short8*>(&Bt[bb][row][(cb ^ (row & 7)) * 8]);
        }
    };
    auto mfma16 = [&](const short8* Af, const short8* Bf, int nh) {
        __builtin_amdgcn_s_setprio(1);
        #pragma unroll
        for (int n = 0; n < 4; ++n)
            #pragma unroll
            for (int m = 0; m < 4; ++m)
                acc[m][nh + n] = __builtin_amdgcn_mfma_f32_16x16x32_bf16(
                    Af[m], Bf[n], acc[m][nh + n], 0, 0, 0);
        __builtin_amdgcn_s_setprio(0);
    };

    // A staging: 1024 elems / 512 thr = 2 per thread (e = tid, tid+512)
    auto loadx_s = [&](int c, float* xv) {
        int i0 = c * 8;
        const float* xs = (i0 < 512) ? rgb : tac;
        int ic = i0 & 511;
        #pragma unroll
        for (int rep = 0; rep < 2; ++rep) {
            int e = tid + rep * 512;
            xv[rep] = xs[(size_t)(b0 + (e >> 3)) * 512 + ic + (e & 7)];
        }
    };
    auto loadx_b = [&](int c, f32x4* xq) {          // base: 16 x/thread
        int i0 = (c - SPLINE_CHUNKS) * 64;
        const float* xs = (i0 < 512) ? rgb : tac;
        int ic = i0 & 511;
        #pragma unroll
        for (int rep = 0; rep < 2; ++rep) {
            int gq = tid + rep * 512;
            const float* xp = xs + (size_t)(b0 + (gq >> 3)) * 512 + ic + (gq & 7) * 8;
            xq[rep * 2]     = *reinterpret_cast<const f32x4*>(xp);
            xq[rep * 2 + 1] = *reinterpret_cast<const f32x4*>(xp + 4);
        }
    };
    auto silupack = [&](const f32x4& xa, const f32x4& xb, unsigned* o) {
        float s[8];
        #pragma unroll
        for (int q = 0; q < 4; ++q) {
            float a = xa[q];
            s[q]     = a * __builtin_amdgcn_rcpf(1.f + __expf(-a));
            float b = xb[q];
            s[q + 4] = b * __builtin_amdgcn_rcpf(1.f + __expf(-b));
        }
        #pragma unroll
        for (int q = 0; q < 4; ++q)
            asm("v_cvt_pk_bf16_f32 %0, %1, %2"
                : "=v"(o[q]) : "v"(s[2 * q]), "v"(s[2 * q + 1]));
    };
    auto writeA = [&](const unsigned* o8, int ab) { // 2 x ds_write_b128
        #pragma unroll
        for (int rep = 0; rep < 2; ++rep) {
            int e = tid + rep * 512;
            int r = e >> 3;
            int c = e & 7;
            *reinterpret_cast<short8*>(&At[ab][r][(c ^ (r & 7)) * 8]) =
                *reinterpret_cast<const short8*>(o8 + rep * 4);
        }
    };
    auto gload_B = [&](int kc, int buf) {           // 8 loads/wave
        int k0g = kc * BK;
        #pragma unroll
        for (int rp = 0; rp < 8; ++rp) {
            int row0 = wid * 64 + rp * 8;           // wave-uniform LDS base
            const unsigned short* gp =
                Wp + (size_t)(row0 + (lane >> 3)) * KTOT + k0g + (lane & 7) * 8;
            __builtin_amdgcn_global_load_lds(
                (const __attribute__((address_space(1))) unsigned int*)gp,
                (__attribute__((address_space(3))) unsigned int*)&Bt[buf][row0][0],
                16, 0, 0);
        }
    };

    // ---------------- prologue (kc0 is always a spline chunk) --------------
    float xc[2];
    {
        float x0[2];
        loadx_s(kc0, x0);
        gload_B(kc0, 0);
        unsigned o8[8];
        basis8(x0[0], o8);
        basis8(x0[1], o8 + 4);
        writeA(o8, 0);
        loadx_s(kc0 + 1 < kcS ? kc0 + 1 : kcS - 1, xc);
        asm volatile("s_waitcnt vmcnt(0) lgkmcnt(0)" ::: "memory");
        __builtin_amdgcn_sched_barrier(0);
        __builtin_amdgcn_s_barrier();
        __builtin_amdgcn_sched_barrier(0);
    }

    // ---------------- spline loop: [kc0, kcS), 4 phases/chunk --------------
    for (int t = kc0; t < kcS; ++t) {
        const int  buf   = (t - kc0) & 1;
        const int  nbuf  = buf ^ 1;
        const bool moreA = (t + 1 < kcS);
        short8 Af[4], Bf[4];
        unsigned o8[8];
        float xn2[2];
        // ===== P0: ks0, n0..3 ; issue x(t+2) + ALL 8 B(t+1) gloads =====
        readA(Af, buf, 0);
        readB(Bf, buf, 0, 0);
        loadx_s(t + 2 < kcS ? t + 2 : kcS - 1, xn2);
        gload_B(t + 1 < kc1 ? t + 1 : kc1 - 1, nbuf);
        PHASE_PRE();
        mfma16(Af, Bf, 0);
        PHASE_POST();
        // ===== P1: ks0, n4..7 ; basis #1 =====
        readB(Bf, buf, 0, 4);
        if (moreA) basis8(xc[0], o8);
        PHASE_PRE();
        mfma16(Af, Bf, 4);
        PHASE_POST();
        // ===== P2: ks1, n0..3 ; basis #2 =====
        readA(Af, buf, 1);
        readB(Bf, buf, 1, 0);
        if (moreA) basis8(xc[1], o8 + 4);
        PHASE_PRE();
        mfma16(Af, Bf, 0);
        PHASE_POST();
        // ===== P3: ks1, n4..7 ; writeA(t+1) ; publish =====
        readB(Bf, buf, 1, 4);
        if (moreA) writeA(o8, nbuf);
        PHASE_PRE();
        mfma16(Af, Bf, 4);
        asm volatile("s_waitcnt vmcnt(0)" ::: "memory");  // issued in P0: free
        PHASE_POST();
        xc[0] = xn2[0]; xc[1] = xn2[1];
    }

    // ---------------- base phase: [kcS, kc1), 4 phases/chunk ---------------
    if (kcS < kc1) {
        f32x4 xq[4];
        {   // transition: stage A(kcS) via silu; B(kcS) already published
            f32x4 x0[4];
            loadx_b(kcS, x0);
            unsigned o8[8];
            silupack(x0[0], x0[1], o8);
            silupack(x0[2], x0[3], o8 + 4);
            writeA(o8, (kcS - kc0) & 1);
            loadx_b(kcS + 1 < kc1 ? kcS + 1 : kc1 - 1, xq);
            asm volatile("s_waitcnt lgkmcnt(0)" ::: "memory");
            __builtin_amdgcn_sched_barrier(0);
            __builtin_amdgcn_s_barrier();
            __builtin_amdgcn_sched_barrier(0);
        }
        for (int t = kcS; t < kc1; ++t) {
            const int  buf   = (t - kc0) & 1;
            const int  nbuf  = buf ^ 1;
            const bool moreA = (t + 1 < kc1);
            short8 Af[4], Bf[4];
            unsigned o8[8];
            f32x4 xn2[4];
            // ===== P0 =====
            readA(Af, buf, 0);
            readB(Bf, buf, 0, 0);
            loadx_b(t + 2 < kc1 ? t + 2 : kc1 - 1, xn2);
            gload_B(t + 1 < kc1 ? t + 1 : kc1 - 1, nbuf);
            PHASE_PRE();
            mfma16(Af, Bf, 0);
            PHASE_POST();
            // ===== P1 =====
            readB(Bf, buf, 0, 4);
            if (moreA) silupack(xq[0], xq[1], o8);
            PHASE_PRE();
            mfma16(Af, Bf, 4);
            PHASE_POST();
            // ===== P2 =====
            readA(Af, buf, 1);
            readB(Bf, buf, 1, 0);
            if (moreA) silupack(xq[2], xq[3], o8 + 4);
            PHASE_PRE();
            mfma16(Af, Bf, 0);
            PHASE_POST();
            // ===== P3 =====
            readB(Bf, buf, 1, 4);
            if (moreA) writeA(o8, nbuf);
            PHASE_PRE();
            mfma16(Af, Bf, 4);
            asm volatile("s_waitcnt vmcnt(0)" ::: "memory");
            PHASE_POST();
            #pragma unroll
            for (int q = 0; q < 4; ++q) xq[q] = xn2[q];
        }
    }

    // ---------------- epilogue: f32 partial store ----------------
    #pragma unroll
    for (int m = 0; m < 4; ++m) {
        int row = b0 + wr * 64 + m * 16 + ((lane >> 4) << 2);
        #pragma unroll
        for (int n = 0; n < 8; ++n) {
            int col = wc * 128 + n * 16 + (lane & 15);
            #pragma unroll
            for (int jj = 0; jj < 4; ++jj)
                dest[(size_t)(row + jj) * OUT_DIM + col] = acc[m][n][jj];
        }
    }
}

// ---------------------------------------------------------------------------
// reduce partials + LayerNorm: out = LN(P0 + P1). One wave per row.
// ---------------------------------------------------------------------------
__global__ void reduce_ln_kernel(const float* __restrict__ P0,
                                 const float* __restrict__ P1,
                                 const float* __restrict__ gamma,
                                 const float* __restrict__ beta,
                                 float* __restrict__ out) {
    int row  = blockIdx.x * 4 + (threadIdx.x >> 6);
    int lane = threadIdx.x & 63;
    const float* p0 = P0 + (size_t)row * OUT_DIM;
    const float* p1 = P1 + (size_t)row * OUT_DIM;
    f32x4 a0 = *reinterpret_cast<const f32x4*>(p0 + lane * 4);
    f32x4 a1 = *reinterpret_cast<const f32x4*>(p0 + 256 + lane * 4);
    f32x4 b0 = *reinterpret_cast<const f32x4*>(p1 + lane * 4);
    f32x4 b1 = *reinterpret_cast<const f32x4*>(p1 + 256 + lane * 4);
    f32x4 v0, v1;
    #pragma unroll
    for (int q = 0; q < 4; ++q) { v0[q] = a0[q] + b0[q]; v1[q] = a1[q] + b1[q]; }
    float s = 0.f, ss = 0.f;
    #pragma unroll
    for (int q = 0; q < 4; ++q) {
        s  += v0[q] + v1[q];
        ss += v0[q] * v0[q] + v1[q] * v1[q];
    }
    #pragma unroll
    for (int off = 1; off < 64; off <<= 1) {
        s  += __shfl_xor(s, off);
        ss += __shfl_xor(ss, off);
    }
    float mu  = s * (1.f / 512.f);
    float var = ss * (1.f / 512.f) - mu * mu;
    float rs  = rsqrtf(var + 1e-5f);
    f32x4 g0 = *reinterpret_cast<const f32x4*>(gamma + lane * 4);
    f32x4 g1 = *reinterpret_cast<const f32x4*>(gamma + 256 + lane * 4);
    f32x4 e0 = *reinterpret_cast<const f32x4*>(beta + lane * 4);
    f32x4 e1 = *reinterpret_cast<const f32x4*>(beta + 256 + lane * 4);
    float* po = out + (size_t)row * OUT_DIM;
    f32x4 r0, r1;
    #pragma unroll
    for (int q = 0; q < 4; ++q) {
        r0[q] = (v0[q] - mu) * rs * g0[q] + e0[q];
        r1[q] = (v1[q] - mu) * rs * g1[q] + e1[q];
    }
    *reinterpret_cast<f32x4*>(po + lane * 4)       = r0;
    *reinterpret_cast<f32x4*>(po + 256 + lane * 4) = r1;
}

// ---------------------------------------------------------------------------
// LayerNorm in place (fallback path, no split).
// ---------------------------------------------------------------------------
__global__ void ln_kernel(float* __restrict__ io,
                          const float* __restrict__ gamma,
                          const float* __restrict__ beta) {
    int row  = blockIdx.x * 4 + (threadIdx.x >> 6);
    int lane = threadIdx.x & 63;
    float* p = io + (size_t)row * OUT_DIM;
    f32x4 v0 = *reinterpret_cast<const f32x4*>(p + lane * 4);
    f32x4 v1 = *reinterpret_cast<const f32x4*>(p + 256 + lane * 4);
    float s = 0.f, ss = 0.f;
    #pragma unroll
    for (int q = 0; q < 4; ++q) {
        s  += v0[q] + v1[q];
        ss += v0[q] * v0[q] + v1[q] * v1[q];
    }
    #pragma unroll
    for (int off = 1; off < 64; off <<= 1) {
        s  += __shfl_xor(s, off);
        ss += __shfl_xor(ss, off);
    }
    float mu  = s * (1.f / 512.f);
    float var = ss * (1.f / 512.f) - mu * mu;
    float rs  = rsqrtf(var + 1e-5f);
    f32x4 g0 = *reinterpret_cast<const f32x4*>(gamma + lane * 4);
    f32x4 g1 = *reinterpret_cast<const f32x4*>(gamma + 256 + lane * 4);
    f32x4 e0 = *reinterpret_cast<const f32x4*>(beta + lane * 4);
    f32x4 e1 = *reinterpret_cast<const f32x4*>(beta + 256 + lane * 4);
    f32x4 r0, r1;
    #pragma unroll
    for (int q = 0; q < 4; ++q) {
        r0[q] = (v0[q] - mu) * rs * g0[q] + e0[q];
        r1[q] = (v1[q] - mu) * rs * g1[q] + e1[q];
    }
    *reinterpret_cast<f32x4*>(p + lane * 4)       = r0;
    *reinterpret_cast<f32x4*>(p + 256 + lane * 4) = r1;
}

// ---------------------------------------------------------------------------
extern "C" void kernel_launch(void* const* d_in, const int* in_sizes, int n_in,
                              void* d_out, int out_size, void* d_ws, size_t ws_size,
                              hipStream_t stream) {
    const float* rgb   = (const float*)d_in[0];
    const float* tac   = (const float*)d_in[1];
    const float* bw    = (const float*)d_in[2];
    const float* sw    = (const float*)d_in[3];
    const float* sc    = (const float*)d_in[4];
    const float* gamma = (const float*)d_in[5];
    const float* beta  = (const float*)d_in[6];
    float* out = (float*)d_out;
    unsigned short* Wp = (unsigned short*)d_ws;        // 9.4 MB at ws[0]

    prep_w_kernel<<<2304, 256, 0, stream>>>(bw, sw, sc, Wp);

    const size_t PART = (size_t)BATCH * OUT_DIM * sizeof(float);   // 32 MB
    const size_t POFF = 16ull << 20;                               // 16 MB
    if (ws_size >= POFF + 2 * PART) {
        // split-K=2: grid (128, 2) = 256 blocks = 1/CU, partials in ws
        float* P = (float*)((char*)d_ws + POFF);
        dim3 g(BATCH / BM, 2);
        kan_gemm_kernel<true><<<g, 512, 0, stream>>>(rgb, tac, Wp, P);
        reduce_ln_kernel<<<BATCH / 4, 256, 0, stream>>>(
            P, P + (size_t)BATCH * OUT_DIM, gamma, beta, out);
    } else {
        // fallback: full K in one pass, LN in place
        dim3 g(BATCH / BM, 1);
        kan_gemm_kernel<false><<<g, 512, 0, stream>>>(rgb, tac, Wp, out);
        ln_kernel<<<BATCH / 4, 256, 0, stream>>>(out, gamma, beta);
    }
}

// Round 15
// 183.699 us; speedup vs baseline: 1.1324x; 1.1324x over previous
//
#include <hip/hip_runtime.h>
#include <cstdint>
#include <cstddef>

// ---------------------------------------------------------------------------
// KANAdaptiveFusion: fused = [bases(x) | silu(x)] @ W'^T ; LayerNorm over OUT.
// Round 15 = revert to Round 8 (measured best, 185 us; R14's 32x32 variant
// raced on graph replay with no perf upside). R8: counted-vmcnt pipeline,
// A double-buffered (2x16 KB), B(t+2) issued right after barrier #A, waited
// with vmcnt(4) (never 0). LDS = 160 KB. Split-K=2, 1024 thr (16 waves 2x8,
// 64x64/wave), chunk-XOR swizzle, pre-swizzled W'.
// ---------------------------------------------------------------------------

#define BATCH    16384
#define OUT_DIM  512
#define KTOT     9216
#define BM       128
#define BK       64
#define NCHUNK        144
#define SPLINE_CHUNKS 128

typedef __attribute__((ext_vector_type(8))) short  short8;
typedef __attribute__((ext_vector_type(4))) float  f32x4;

static __device__ __forceinline__ unsigned short f2bf(float f) {
    unsigned int u = __float_as_uint(f);
    unsigned int r = u + 0x7fffu + ((u >> 16) & 1u);
    return (unsigned short)(r >> 16);
}

// ---------------------------------------------------------------------------
// prep: W' bf16 (OUT_DIM x KTOT row-major) PRE-SWIZZLED: within each 64-elem
// K-block, 8-element chunk cl stored at chunk cl ^ (o&7).  (proven)
// ---------------------------------------------------------------------------
__global__ void prep_w_kernel(const float* __restrict__ bw,
                              const float* __restrict__ sw,
                              const float* __restrict__ sc,
                              unsigned short* __restrict__ Wp) {
    int t = blockIdx.x * 256 + threadIdx.x;      // < 512 * 1152
    int o = t / 1152;
    int g = t - o * 1152;
    int sz = o & 7;
    unsigned short o8[8];
    size_t dst;
    if (g < 1024) {                 // spline region: i = g, coefs 0..7
        float s = sc[(size_t)o * 1024 + g];
        const float* w = sw + ((size_t)o * 1024 + g) * 8;
        #pragma unroll
        for (int k = 0; k < 8; ++k) o8[k] = f2bf(w[k] * s);
        dst = (size_t)o * KTOT + (size_t)(g >> 3) * 64 + (size_t)(((g & 7) ^ sz)) * 8;
    } else {                        // base region
        int gi = g - 1024;          // 0..127
        const float* w = bw + (size_t)o * 1024 + gi * 8;
        #pragma unroll
        for (int k = 0; k < 8; ++k) o8[k] = f2bf(w[k]);
        dst = (size_t)o * KTOT + (size_t)8192 + (size_t)(gi >> 3) * 64 + (size_t)(((gi & 7) ^ sz)) * 8;
    }
    *reinterpret_cast<short8*>(Wp + dst) = *reinterpret_cast<const short8*>(o8);
}

// ---------------------------------------------------------------------------
// basis8: cubic B-spline bases packed as 4 u32 (8 bf16). (proven in R7)
// ---------------------------------------------------------------------------
static __device__ __forceinline__ void basis8(float x, unsigned* out) {
    float tpos = (x + 2.2f) * 2.5f;          // knots -2.2 + 0.4*t
    float fj   = floorf(tpos);
    int   j    = (int)fj;
    float u  = tpos - fj;
    float v  = 1.f - u;
    float u2 = u * u;
    float u3 = u2 * u;
    const float c6 = 1.f / 6.f;
    float n0 = v * v * v * c6;
    float n1 = (3.f * u3 - 6.f * u2 + 4.f) * c6;
    float n2 = (-3.f * u3 + 3.f * u2 + 3.f * u + 1.f) * c6;
    float n3 = u3 * c6;
    unsigned p0, p1;
    asm("v_cvt_pk_bf16_f32 %0, %1, %2" : "=v"(p0) : "v"(n0), "v"(n1));
    asm("v_cvt_pk_bf16_f32 %0, %1, %2" : "=v"(p1) : "v"(n2), "v"(n3));
    int sh = (j << 4) - 48;                  // bf16-slot shift *16
    int c  = sh & 16;
    int w  = (sh - c) >> 5;                  // signed word shift
    unsigned long long P = ((unsigned long long)p1 << 32) | p0;
    unsigned long long T = P << c;
    unsigned t0 = (unsigned)T;
    unsigned t1 = (unsigned)(T >> 32);
    unsigned t2 = c ? (p1 >> 16) : 0u;
    #pragma unroll
    for (int i = 0; i < 4; ++i) {
        unsigned r = 0u;
        r = (w == i    ) ? t0 : r;
        r = (w == i - 1) ? t1 : r;
        r = (w == i - 2) ? t2 : r;
        out[i] = r;
    }
}

// ---------------------------------------------------------------------------
// GEMM: 128x512 tile, BK=64, 1024 threads (16 waves 2x8; 64x64 per wave).
// A dbuf 2x16 KB + B dbuf 2x64 KB = 160 KB.
// ---------------------------------------------------------------------------
template<bool SPLIT>
__launch_bounds__(1024, 4)
__global__ void kan_gemm_kernel(const float* __restrict__ rgb,
                                const float* __restrict__ tac,
                                const unsigned short* __restrict__ Wp,
                                float* __restrict__ dest_base) {
    __shared__ unsigned short At[2][BM][BK];        //  32 KB, chunk-swizzled
    __shared__ unsigned short Bt[2][OUT_DIM][BK];   // 128 KB, chunk-swizzled

    const int tid  = threadIdx.x;
    const int lane = tid & 63;
    const int wid  = tid >> 6;
    const int b0   = blockIdx.x * BM;
    const int wr   = wid & 1;                       // 2 m-waves (64 rows)
    const int wc   = wid >> 1;                      // 8 n-waves (64 cols)
    const int ksp  = SPLIT ? (int)blockIdx.y : 0;
    const int kc0  = SPLIT ? (ksp ? 72 : 0)             : 0;
    const int kcS  = SPLIT ? (ksp ? SPLINE_CHUNKS : 72) : SPLINE_CHUNKS;
    const int kc1  = SPLIT ? (ksp ? NCHUNK : 72)        : NCHUNK;
    float* dest = dest_base + (size_t)ksp * BATCH * OUT_DIM;

    const int ar  = tid >> 3;                       // A-staging row 0..127
    const int af_ = tid & 7;                        // A-staging chunk 0..7

    f32x4 acc[4][4];
    #pragma unroll
    for (int m = 0; m < 4; ++m)
        #pragma unroll
        for (int n = 0; n < 4; ++n)
            acc[m][n] = (f32x4){0.f, 0.f, 0.f, 0.f};

    auto mfma_step = [&](int ab, int bb) {
        #pragma unroll
        for (int ks = 0; ks < 2; ++ks) {
            int cb = ks * 4 + (lane >> 4);
            short8 afr[4];
            #pragma unroll
            for (int m = 0; m < 4; ++m) {
                int row = wr * 64 + m * 16 + (lane & 15);
                afr[m] = *reinterpret_cast<const short8*>(&At[ab][row][(cb ^ (row & 7)) * 8]);
            }
            #pragma unroll
            for (int n = 0; n < 4; ++n) {
                int row = wc * 64 + n * 16 + (lane & 15);
                short8 bfr = *reinterpret_cast<const short8*>(
                    &Bt[bb][row][(cb ^ (row & 7)) * 8]);
                #pragma unroll
                for (int m = 0; m < 4; ++m)
                    acc[m][n] = __builtin_amdgcn_mfma_f32_16x16x32_bf16(
                        afr[m], bfr, acc[m][n], 0, 0, 0);
            }
        }
    };

    auto loadx_s = [&](int c) -> float {            // spline: 1 x/thread
        int i0 = c * 8;
        const float* xs = (i0 < 512) ? rgb : tac;
        int ic = i0 & 511;
        return xs[(size_t)(b0 + ar) * 512 + ic + af_];
    };

    auto loadx_b = [&](int c, f32x4& xa, f32x4& xb) {  // base: 8 x/thread
        int i0 = (c - SPLINE_CHUNKS) * 64;
        const float* xs = (i0 < 512) ? rgb : tac;
        int ic = i0 & 511;
        const float* xp = xs + (size_t)(b0 + ar) * 512 + ic + af_ * 8;
        xa = *reinterpret_cast<const f32x4*>(xp);
        xb = *reinterpret_cast<const f32x4*>(xp + 4);
    };

    auto silupack = [&](const f32x4& xa, const f32x4& xb, unsigned* o) {
        float s[8];
        #pragma unroll
        for (int q = 0; q < 4; ++q) {
            float a = xa[q]; s[q]     = a / (1.f + __expf(-a));
            float b = xb[q]; s[q + 4] = b / (1.f + __expf(-b));
        }
        #pragma unroll
        for (int q = 0; q < 4; ++q)
            asm("v_cvt_pk_bf16_f32 %0, %1, %2"
                : "=v"(o[q]) : "v"(s[2 * q]), "v"(s[2 * q + 1]));
    };

    auto writeA = [&](const unsigned* o4, int ab) {
        *reinterpret_cast<short8*>(&At[ab][ar][(af_ ^ (ar & 7)) * 8]) =
            *reinterpret_cast<const short8*>(o4);
    };

    auto gload_B = [&](int kc, int buf) {
        int k0g = kc * BK;
        #pragma unroll
        for (int rp = 0; rp < 4; ++rp) {
            int row0 = wid * 32 + rp * 8;           // wave-uniform LDS base
            const unsigned short* gp =
                Wp + (size_t)(row0 + (lane >> 3)) * KTOT + k0g + (lane & 7) * 8;
            __builtin_amdgcn_global_load_lds(
                (const __attribute__((address_space(1))) unsigned int*)gp,
                (__attribute__((address_space(3))) unsigned int*)&Bt[buf][row0][0],
                16, 0, 0);
        }
    };

    // ---------------- prologue (kc0 is always a spline chunk) --------------
    gload_B(kc0, 0);
    gload_B(kc0 + 1 < kc1 ? kc0 + 1 : kc1 - 1, 1);
    {
        float x0 = loadx_s(kc0);
        unsigned o4[4];
        basis8(x0, o4);
        writeA(o4, 0);
    }
    float xn = (kc0 + 1 < kcS) ? loadx_s(kc0 + 1) : 0.f;
    asm volatile("s_waitcnt vmcnt(4) lgkmcnt(0)" ::: "memory");
    __builtin_amdgcn_sched_barrier(0);
    __builtin_amdgcn_s_barrier();
    __builtin_amdgcn_sched_barrier(0);

    // ---------------- spline loop: [kc0, kcS) ----------------
    for (int t = kc0; t < kcS; ++t) {
        const int  buf   = (t - kc0) & 1;           // B(t)/A(t) parity
        const bool moreA = (t + 1 < kcS);
        unsigned o4[4];
        if (moreA) {                                 // A(t+1): VALU || MFMA
            basis8(xn, o4);
            writeA(o4, buf ^ 1);
        }
        if (t + 2 < kcS) xn = loadx_s(t + 2);        // x(t+2) issued early
        mfma_step(buf, buf);
        __builtin_amdgcn_sched_barrier(0);
        __builtin_amdgcn_s_barrier();                // #A: buffers t free
        __builtin_amdgcn_sched_barrier(0);
        int tn = (t + 2 < kc1) ? t + 2 : kc1 - 1;
        gload_B(tn, buf);                            // B(t+2) into freed buf
        asm volatile("s_waitcnt vmcnt(4) lgkmcnt(0)" ::: "memory"); // B(t+1) done
        __builtin_amdgcn_sched_barrier(0);
        __builtin_amdgcn_s_barrier();                // #B: publish t+1
        __builtin_amdgcn_sched_barrier(0);
    }

    // ---------------- base phase: [kcS, kc1) ----------------
    if (kcS < kc1) {
        f32x4 xa{}, xb{};
        {   // stage A(kcS); B(kcS) already published, B(kcS+1) in flight
            f32x4 a0, b0;
            loadx_b(kcS, a0, b0);
            unsigned o4[4];
            silupack(a0, b0, o4);
            writeA(o4, (kcS - kc0) & 1);
            if (kcS + 1 < kc1) loadx_b(kcS + 1, xa, xb);
            asm volatile("s_waitcnt lgkmcnt(0)" ::: "memory");
            __builtin_amdgcn_sched_barrier(0);
            __builtin_amdgcn_s_barrier();            // publish A(kcS)
            __builtin_amdgcn_sched_barrier(0);
        }
        for (int t = kcS; t < kc1; ++t) {
            const int  buf   = (t - kc0) & 1;
            const bool moreA = (t + 1 < kc1);
            unsigned o4[4];
            if (moreA) {
                silupack(xa, xb, o4);
                writeA(o4, buf ^ 1);
            }
            f32x4 na, nb;
            const bool moreX = (t + 2 < kc1);
            if (moreX) loadx_b(t + 2, na, nb);
            mfma_step(buf, buf);
            __builtin_amdgcn_sched_barrier(0);
            __builtin_amdgcn_s_barrier();            // #A
            __builtin_amdgcn_sched_barrier(0);
            int tn = moreX ? t + 2 : kc1 - 1;
            gload_B(tn, buf);
            asm volatile("s_waitcnt vmcnt(4) lgkmcnt(0)" ::: "memory");
            __builtin_amdgcn_sched_barrier(0);
            __builtin_amdgcn_s_barrier();            // #B
            __builtin_amdgcn_sched_barrier(0);
            if (moreX) { xa = na; xb = nb; }
        }
    }

    // ---------------- epilogue: f32 partial store ----------------
    #pragma unroll
    for (int m = 0; m < 4; ++m) {
        int row = b0 + wr * 64 + m * 16 + ((lane >> 4) << 2);
        #pragma unroll
        for (int n = 0; n < 4; ++n) {
            int col = wc * 64 + n * 16 + (lane & 15);
            #pragma unroll
            for (int jj = 0; jj < 4; ++jj)
                dest[(size_t)(row + jj) * OUT_DIM + col] = acc[m][n][jj];
        }
    }
}

// ---------------------------------------------------------------------------
// reduce partials + LayerNorm: out = LN(P0 + P1). One wave per row.
// ---------------------------------------------------------------------------
__global__ void reduce_ln_kernel(const float* __restrict__ P0,
                                 const float* __restrict__ P1,
                                 const float* __restrict__ gamma,
                                 const float* __restrict__ beta,
                                 float* __restrict__ out) {
    int row  = blockIdx.x * 4 + (threadIdx.x >> 6);
    int lane = threadIdx.x & 63;
    const float* p0 = P0 + (size_t)row * OUT_DIM;
    const float* p1 = P1 + (size_t)row * OUT_DIM;
    f32x4 a0 = *reinterpret_cast<const f32x4*>(p0 + lane * 4);
    f32x4 a1 = *reinterpret_cast<const f32x4*>(p0 + 256 + lane * 4);
    f32x4 b0 = *reinterpret_cast<const f32x4*>(p1 + lane * 4);
    f32x4 b1 = *reinterpret_cast<const f32x4*>(p1 + 256 + lane * 4);
    f32x4 v0, v1;
    #pragma unroll
    for (int q = 0; q < 4; ++q) { v0[q] = a0[q] + b0[q]; v1[q] = a1[q] + b1[q]; }
    float s = 0.f, ss = 0.f;
    #pragma unroll
    for (int q = 0; q < 4; ++q) {
        s  += v0[q] + v1[q];
        ss += v0[q] * v0[q] + v1[q] * v1[q];
    }
    #pragma unroll
    for (int off = 1; off < 64; off <<= 1) {
        s  += __shfl_xor(s, off);
        ss += __shfl_xor(ss, off);
    }
    float mu  = s * (1.f / 512.f);
    float var = ss * (1.f / 512.f) - mu * mu;
    float rs  = rsqrtf(var + 1e-5f);
    f32x4 g0 = *reinterpret_cast<const f32x4*>(gamma + lane * 4);
    f32x4 g1 = *reinterpret_cast<const f32x4*>(gamma + 256 + lane * 4);
    f32x4 e0 = *reinterpret_cast<const f32x4*>(beta + lane * 4);
    f32x4 e1 = *reinterpret_cast<const f32x4*>(beta + 256 + lane * 4);
    float* po = out + (size_t)row * OUT_DIM;
    f32x4 r0, r1;
    #pragma unroll
    for (int q = 0; q < 4; ++q) {
        r0[q] = (v0[q] - mu) * rs * g0[q] + e0[q];
        r1[q] = (v1[q] - mu) * rs * g1[q] + e1[q];
    }
    *reinterpret_cast<f32x4*>(po + lane * 4)       = r0;
    *reinterpret_cast<f32x4*>(po + 256 + lane * 4) = r1;
}

// ---------------------------------------------------------------------------
// LayerNorm in place (fallback path, no split).
// ---------------------------------------------------------------------------
__global__ void ln_kernel(float* __restrict__ io,
                          const float* __restrict__ gamma,
                          const float* __restrict__ beta) {
    int row  = blockIdx.x * 4 + (threadIdx.x >> 6);
    int lane = threadIdx.x & 63;
    float* p = io + (size_t)row * OUT_DIM;
    f32x4 v0 = *reinterpret_cast<const f32x4*>(p + lane * 4);
    f32x4 v1 = *reinterpret_cast<const f32x4*>(p + 256 + lane * 4);
    float s = 0.f, ss = 0.f;
    #pragma unroll
    for (int q = 0; q < 4; ++q) {
        s  += v0[q] + v1[q];
        ss += v0[q] * v0[q] + v1[q] * v1[q];
    }
    #pragma unroll
    for (int off = 1; off < 64; off <<= 1) {
        s  += __shfl_xor(s, off);
        ss += __shfl_xor(ss, off);
    }
    float mu  = s * (1.f / 512.f);
    float var = ss * (1.f / 512.f) - mu * mu;
    float rs  = rsqrtf(var + 1e-5f);
    f32x4 g0 = *reinterpret_cast<const f32x4*>(gamma + lane * 4);
    f32x4 g1 = *reinterpret_cast<const f32x4*>(gamma + 256 + lane * 4);
    f32x4 e0 = *reinterpret_cast<const f32x4*>(beta + lane * 4);
    f32x4 e1 = *reinterpret_cast<const f32x4*>(beta + 256 + lane * 4);
    f32x4 r0, r1;
    #pragma unroll
    for (int q = 0; q < 4; ++q) {
        r0[q] = (v0[q] - mu) * rs * g0[q] + e0[q];
        r1[q] = (v1[q] - mu) * rs * g1[q] + e1[q];
    }
    *reinterpret_cast<f32x4*>(p + lane * 4)       = r0;
    *reinterpret_cast<f32x4*>(p + 256 + lane * 4) = r1;
}

// ---------------------------------------------------------------------------
extern "C" void kernel_launch(void* const* d_in, const int* in_sizes, int n_in,
                              void* d_out, int out_size, void* d_ws, size_t ws_size,
                              hipStream_t stream) {
    const float* rgb   = (const float*)d_in[0];
    const float* tac   = (const float*)d_in[1];
    const float* bw    = (const float*)d_in[2];
    const float* sw    = (const float*)d_in[3];
    const float* sc    = (const float*)d_in[4];
    const float* gamma = (const float*)d_in[5];
    const float* beta  = (const float*)d_in[6];
    float* out = (float*)d_out;
    unsigned short* Wp = (unsigned short*)d_ws;        // 9.4 MB at ws[0]

    prep_w_kernel<<<2304, 256, 0, stream>>>(bw, sw, sc, Wp);

    const size_t PART = (size_t)BATCH * OUT_DIM * sizeof(float);   // 32 MB
    const size_t POFF = 16ull << 20;                               // 16 MB
    if (ws_size >= POFF + 2 * PART) {
        // split-K=2: grid (128, 2) = 256 blocks = 1/CU, partials in ws
        float* P = (float*)((char*)d_ws + POFF);
        dim3 g(BATCH / BM, 2);
        kan_gemm_kernel<true><<<g, 1024, 0, stream>>>(rgb, tac, Wp, P);
        reduce_ln_kernel<<<BATCH / 4, 256, 0, stream>>>(
            P, P + (size_t)BATCH * OUT_DIM, gamma, beta, out);
    } else {
        // fallback: full K in one pass, LN in place
        dim3 g(BATCH / BM, 1);
        kan_gemm_kernel<false><<<g, 1024, 0, stream>>>(rgb, tac, Wp, out);
        ln_kernel<<<BATCH / 4, 256, 0, stream>>>(out, gamma, beta);
    }
}